// Round 9
// baseline (504.433 us; speedup 1.0000x reference)
//
#include <hip/hip_runtime.h>
#include <hip/hip_bf16.h>
#include <math.h>

#define BN    32
#define NTOK  785
#define GH    28
#define GW    28
#define DIM   768
#define QKVD  2304
#define NH    8
#define HD    96
#define MROWS (BN*NTOK)   // 25120
#define NS    4           // attn token-split
#define NPC   197         // ceil(785/4)

typedef __hip_bfloat16 bf16;
typedef unsigned short ushort_t;
typedef short s16x8 __attribute__((ext_vector_type(8)));   // 8 bf16 = 4 VGPRs
typedef float f32x4 __attribute__((ext_vector_type(4)));   // MFMA acc

// ---------------------------------------------------------------------------
// helpers
// ---------------------------------------------------------------------------
__device__ __forceinline__ void gl2lds16(const void* g, void* l) {
    // 16B per lane, LDS dest = wave-uniform base + lane*16
    __builtin_amdgcn_global_load_lds(
        (__attribute__((address_space(1))) void*)const_cast<void*>(g),
        (__attribute__((address_space(3))) void*)l, 16, 0, 0);
}

__device__ __forceinline__ ushort_t f2bf(float f) {
    bf16 h = __float2bfloat16(f);
    return *(ushort_t*)&h;
}

__device__ __forceinline__ float bf2f(ushort_t u) {
    return __bfloat162float(*(const bf16*)&u);
}

__device__ __forceinline__ s16x8 cvt8(const float* p) {   // 8 fp32 (LDS) -> bf16x8
    float4 a = *(const float4*)p;
    float4 b = *(const float4*)(p + 4);
    union { s16x8 v; __hip_bfloat162 h[4]; } r;
    r.h[0] = __float22bfloat162_rn(make_float2(a.x, a.y));
    r.h[1] = __float22bfloat162_rn(make_float2(a.z, a.w));
    r.h[2] = __float22bfloat162_rn(make_float2(b.x, b.y));
    r.h[3] = __float22bfloat162_rn(make_float2(b.z, b.w));
    return r.v;
}

// bijective XCD swizzle (m204): contiguous tile chunks per XCD.
__device__ __forceinline__ int xcd_swizzle(int orig, int nwg) {
    int qd = nwg >> 3, r8 = nwg & 7;
    int xcd = orig & 7, idx = orig >> 3;
    return (xcd < r8 ? xcd * (qd + 1) : r8 * (qd + 1) + (xcd - r8) * qd) + idx;
}

// ---------------------------------------------------------------------------
// K-1: merged prep. Flattened 1D grid:
//  blocks [0, 1728)        : transpose W_qkv fp32[768][2304] -> Wqkvt bf16[2304][768]
//  blocks [1728, 2304)     : transpose W_out fp32[768][768]  -> Wot bf16[768][768]
//  blocks [2304, 2304+9420): convert x fp32 -> xb bf16 (8 elems/thread)
// ---------------------------------------------------------------------------
#define TQKV  1728   // (QKVD/32)*(DIM/32)
#define TOUT  576    // (DIM/32)*(DIM/32)
#define NCONV 9420   // MROWS*DIM/8/256

__global__ __launch_bounds__(256)
void prep_kernel(const float* __restrict__ W_qkv, ushort_t* __restrict__ Wqkvt,
                 const float* __restrict__ W_out, ushort_t* __restrict__ Wot,
                 const float* __restrict__ x, ushort_t* __restrict__ xb) {
    __shared__ float tile[32][33];
    const int bid = blockIdx.x;
    const int tid = threadIdx.x;
    if (bid >= TQKV + TOUT) {
        // convert path
        int i = (bid - TQKV - TOUT) * 256 + tid;
        const float4* p = (const float4*)(x + (size_t)i * 8);
        float4 a = p[0], b = p[1];
        union { s16x8 v; __hip_bfloat162 h[4]; } r;
        r.h[0] = __float22bfloat162_rn(make_float2(a.x, a.y));
        r.h[1] = __float22bfloat162_rn(make_float2(a.z, a.w));
        r.h[2] = __float22bfloat162_rn(make_float2(b.x, b.y));
        r.h[3] = __float22bfloat162_rn(make_float2(b.z, b.w));
        *(s16x8*)(xb + (size_t)i * 8) = r.v;
        return;
    }
    // transpose path
    const float* W; ushort_t* Wt; int R, C, loc;
    if (bid < TQKV) { W = W_qkv; Wt = Wqkvt; R = DIM; C = QKVD; loc = bid; }
    else            { W = W_out; Wt = Wot;   R = DIM; C = DIM;  loc = bid - TQKV; }
    const int xt = C / 32;
    const int c0 = (loc % xt) * 32, r0 = (loc / xt) * 32;
    const int tx = tid & 31, ty = tid >> 5;   // 32 x 8
    #pragma unroll
    for (int i = 0; i < 4; ++i)
        tile[ty + i * 8][tx] = W[(size_t)(r0 + ty + i * 8) * C + c0 + tx];
    __syncthreads();
    #pragma unroll
    for (int i = 0; i < 4; ++i)
        Wt[(size_t)(c0 + ty + i * 8) * R + r0 + tx] = f2bf(tile[tx][ty + i * 8]);
}

// ---------------------------------------------------------------------------
// K1: qkv GEMM via MFMA (PROVEN BK=32 shape) + XCD swizzle (r8: ~146 us).
// ---------------------------------------------------------------------------
__global__ __launch_bounds__(256)
void gemm_qkv_mfma(const ushort_t* __restrict__ A, const ushort_t* __restrict__ Bt,
                   const float* __restrict__ bias,
                   ushort_t* __restrict__ q, ushort_t* __restrict__ kk,
                   ushort_t* __restrict__ v) {
    const int M = MROWS, K = DIM;
    __shared__ ushort_t Asm[128 * 32];   // 8 KB
    __shared__ ushort_t Bsm[128 * 32];   // 8 KB
    const int tid  = threadIdx.x;
    const int wave = tid >> 6;
    const int lane = tid & 63;
    const int nwg  = gridDim.x * gridDim.y;
    const int swb  = xcd_swizzle(blockIdx.y * gridDim.x + blockIdx.x, nwg);
    const int row0 = (swb / gridDim.x) * 128;
    const int col0 = (swb % gridDim.x) * 128;
    const int wm = wave >> 1, wn = wave & 1;
    const int q4 = lane >> 4, l15 = lane & 15;
    const int slotg = (lane & 3) ^ ((lane >> 3) & 3);  // staging source slot
    const int swz   = (l15 >> 1) & 3;                  // read-side row xor

    f32x4 acc[4][4];
    #pragma unroll
    for (int i = 0; i < 4; ++i)
        #pragma unroll
        for (int j = 0; j < 4; ++j) acc[i][j] = (f32x4){0.f, 0.f, 0.f, 0.f};

    for (int kt = 0; kt < K; kt += 32) {
        #pragma unroll
        for (int r = 0; r < 2; ++r) {
            int seg = r * 4 + wave;
            int rit = seg * 16 + (lane >> 2);
            int grow = min(row0 + rit, M - 1);
            const ushort_t* gp = A + (size_t)grow * K + kt + slotg * 8;
            gl2lds16(gp, &Asm[seg * 512]);
        }
        #pragma unroll
        for (int r = 0; r < 2; ++r) {
            int seg = r * 4 + wave;
            int nit = seg * 16 + (lane >> 2);
            const ushort_t* gp = Bt + (size_t)(col0 + nit) * K + kt + slotg * 8;
            gl2lds16(gp, &Bsm[seg * 512]);
        }
        __syncthreads();
        s16x8 af[4], bfr[4];
        #pragma unroll
        for (int mi = 0; mi < 4; ++mi)
            af[mi] = *(const s16x8*)&Asm[(wm * 64 + mi * 16 + l15) * 32
                                         + ((q4 ^ swz) * 8)];
        #pragma unroll
        for (int ni = 0; ni < 4; ++ni)
            bfr[ni] = *(const s16x8*)&Bsm[(wn * 64 + ni * 16 + l15) * 32
                                          + ((q4 ^ swz) * 8)];
        #pragma unroll
        for (int mi = 0; mi < 4; ++mi)
            #pragma unroll
            for (int ni = 0; ni < 4; ++ni)
                acc[mi][ni] = __builtin_amdgcn_mfma_f32_16x16x32_bf16(
                    af[mi], bfr[ni], acc[mi][ni], 0, 0, 0);
        __syncthreads();
    }
    int colbase = col0 + wn * 64;
    int seg = colbase / DIM;
    int csub = colbase - seg * DIM;
    ushort_t* outp = (seg == 0) ? q : (seg == 1) ? kk : v;
    #pragma unroll
    for (int mi = 0; mi < 4; ++mi) {
        #pragma unroll
        for (int ni = 0; ni < 4; ++ni) {
            int gcol = colbase + ni * 16 + l15;
            int col  = csub + ni * 16 + l15;
            float bb = bias[gcol];
            #pragma unroll
            for (int j = 0; j < 4; ++j) {
                int row = row0 + wm * 64 + mi * 16 + q4 * 4 + j;
                if (row < M)
                    outp[(size_t)row * DIM + col] = f2bf(acc[mi][ni][j] + bb);
            }
        }
    }
}

// ---------------------------------------------------------------------------
// K6: out GEMM via MFMA (BK=32 proven shape) + XCD swizzle.
// ---------------------------------------------------------------------------
__global__ __launch_bounds__(256)
void gemm_out_mfma(const ushort_t* __restrict__ A, const ushort_t* __restrict__ Bt,
                   const float* __restrict__ bias, float* __restrict__ C) {
    const int M = MROWS, N = DIM, K = DIM;
    __shared__ ushort_t Asm[128 * 32];
    __shared__ ushort_t Bsm[128 * 32];
    const int tid  = threadIdx.x;
    const int wave = tid >> 6;
    const int lane = tid & 63;
    const int nwg  = gridDim.x * gridDim.y;
    const int swb  = xcd_swizzle(blockIdx.y * gridDim.x + blockIdx.x, nwg);
    const int row0 = (swb / gridDim.x) * 128;
    const int col0 = (swb % gridDim.x) * 128;
    const int wm = wave >> 1, wn = wave & 1;
    const int q4 = lane >> 4, l15 = lane & 15;
    const int slotg = (lane & 3) ^ ((lane >> 3) & 3);
    const int swz   = (l15 >> 1) & 3;

    f32x4 acc[4][4];
    #pragma unroll
    for (int i = 0; i < 4; ++i)
        #pragma unroll
        for (int j = 0; j < 4; ++j) acc[i][j] = (f32x4){0.f, 0.f, 0.f, 0.f};

    for (int kt = 0; kt < K; kt += 32) {
        #pragma unroll
        for (int r = 0; r < 2; ++r) {
            int seg = r * 4 + wave;
            int rit = seg * 16 + (lane >> 2);
            int grow = min(row0 + rit, M - 1);
            const ushort_t* gp = A + (size_t)grow * K + kt + slotg * 8;
            gl2lds16(gp, &Asm[seg * 512]);
        }
        #pragma unroll
        for (int r = 0; r < 2; ++r) {
            int seg = r * 4 + wave;
            int nit = seg * 16 + (lane >> 2);
            const ushort_t* gp = Bt + (size_t)(col0 + nit) * K + kt + slotg * 8;
            gl2lds16(gp, &Bsm[seg * 512]);
        }
        __syncthreads();
        s16x8 af[4], bfr[4];
        #pragma unroll
        for (int mi = 0; mi < 4; ++mi)
            af[mi] = *(const s16x8*)&Asm[(wm * 64 + mi * 16 + l15) * 32
                                         + ((q4 ^ swz) * 8)];
        #pragma unroll
        for (int ni = 0; ni < 4; ++ni)
            bfr[ni] = *(const s16x8*)&Bsm[(wn * 64 + ni * 16 + l15) * 32
                                          + ((q4 ^ swz) * 8)];
        #pragma unroll
        for (int mi = 0; mi < 4; ++mi)
            #pragma unroll
            for (int ni = 0; ni < 4; ++ni)
                acc[mi][ni] = __builtin_amdgcn_mfma_f32_16x16x32_bf16(
                    af[mi], bfr[ni], acc[mi][ni], 0, 0, 0);
        __syncthreads();
    }
    #pragma unroll
    for (int mi = 0; mi < 4; ++mi) {
        #pragma unroll
        for (int ni = 0; ni < 4; ++ni) {
            int col = col0 + wn * 64 + ni * 16 + l15;
            float bb = bias[col];
            #pragma unroll
            for (int j = 0; j < 4; ++j) {
                int row = row0 + wm * 64 + mi * 16 + q4 * 4 + j;
                if (row < M)
                    C[(size_t)row * N + col] = acc[mi][ni][j] + bb;
            }
        }
    }
}

// ---------------------------------------------------------------------------
// K2: per-(b,c) softmax stats. 32-ch blocks (grid 24 x BN = 768 = 3/CU,
// was 384 = 1.5/CU latency-exposed). 256 thr = 4 ch-chunks x 64 token-groups.
// red padded [64][33] -> ~2-way banks (was 16-way at [32][64] pattern).
// ---------------------------------------------------------------------------
__global__ __launch_bounds__(256)
void softmax_stats_kernel(const ushort_t* __restrict__ k,
                          float* __restrict__ stat_m, float* __restrict__ stat_is) {
    const int b  = blockIdx.y;
    const int c0 = blockIdx.x * 32;
    const int tid = threadIdx.x;
    const int c8 = tid & 3, tg = tid >> 2;   // chunk 0..3, token-group 0..63
    __shared__ float red[64][33];
    __shared__ float smB[32];
    const ushort_t* base = k + (size_t)b * NTOK * DIM + c0 + c8 * 8;

    float mx[8];
    #pragma unroll
    for (int j = 0; j < 8; ++j) mx[j] = -1e30f;
    for (int n = tg; n < NTOK; n += 64) {
        union { s16x8 v; ushort_t u[8]; } kv;
        kv.v = *(const s16x8*)(base + (size_t)n * DIM);
        #pragma unroll
        for (int j = 0; j < 8; ++j) mx[j] = fmaxf(mx[j], bf2f(kv.u[j]));
    }
    #pragma unroll
    for (int j = 0; j < 8; ++j) red[tg][c8 * 8 + j] = mx[j];
    __syncthreads();
    if (tid < 32) {
        float M = red[0][tid];
        #pragma unroll 8
        for (int i = 1; i < 64; ++i) M = fmaxf(M, red[i][tid]);
        smB[tid] = M;
    }
    __syncthreads();

    float sm8[8], ss[8];
    #pragma unroll
    for (int j = 0; j < 8; ++j) { sm8[j] = smB[c8 * 8 + j]; ss[j] = 0.f; }
    for (int n = tg; n < NTOK; n += 64) {
        union { s16x8 v; ushort_t u[8]; } kv;
        kv.v = *(const s16x8*)(base + (size_t)n * DIM);
        #pragma unroll
        for (int j = 0; j < 8; ++j) ss[j] += __expf(bf2f(kv.u[j]) - sm8[j]);
    }
    __syncthreads();
    #pragma unroll
    for (int j = 0; j < 8; ++j) red[tg][c8 * 8 + j] = ss[j];
    __syncthreads();
    if (tid < 32) {
        float S = 0.f;
        #pragma unroll 8
        for (int i = 0; i < 64; ++i) S += red[i][tid];
        stat_m[b * DIM + c0 + tid]  = smB[tid];
        stat_is[b * DIM + c0 + tid] = 1.f / S;
    }
}

// ---------------------------------------------------------------------------
// K3: attn_part[ns][b,h,d,e] = sum_{n in chunk} exp(k[n,d]-m_d) * v[n,e]
// MFMA version (r6, verified).
// ---------------------------------------------------------------------------
__global__ __launch_bounds__(256)
void attn_kernel(const bf16* __restrict__ k, const bf16* __restrict__ v,
                 const float* __restrict__ stat_m,
                 float* __restrict__ attn_part) {
    const int h = blockIdx.x, b = blockIdx.y, ns = blockIdx.z;
    const int t = threadIdx.x;
    const int wave = t >> 6, lane = t & 63;
    const int q4 = lane >> 4, l15 = lane & 15;
    const int wd = wave >> 1, we = wave & 1;   // quadrant: d-half, e-half
    __shared__ float ekT[96][36];
    __shared__ float vT[96][36];
    __shared__ float smM[96];
    if (t < 96) smM[t] = stat_m[b * DIM + h * HD + t];
    __syncthreads();

    f32x4 acc[3][3];
    #pragma unroll
    for (int i = 0; i < 3; ++i)
        #pragma unroll
        for (int j = 0; j < 3; ++j) acc[i][j] = (f32x4){0.f, 0.f, 0.f, 0.f};

    const bf16* kbase = k + (size_t)b * NTOK * DIM + h * HD;
    const bf16* vbase = v + (size_t)b * NTOK * DIM + h * HD;
    const int nlo = ns * NPC;
    const int nhi = min(NTOK, nlo + NPC);
    const int tl = t >> 3;          // token slot 0..31
    const int cg = (t & 7) * 12;    // channel base 0,12,..,84
    for (int n0 = nlo; n0 < nhi; n0 += 32) {
        const int n = n0 + tl;
        if (n < nhi) {
            #pragma unroll
            for (int j = 0; j < 6; ++j) {
                float2 kf = __bfloat1622float2(
                    *(const __hip_bfloat162*)&kbase[(size_t)n * DIM + cg + 2 * j]);
                float2 vf = __bfloat1622float2(
                    *(const __hip_bfloat162*)&vbase[(size_t)n * DIM + cg + 2 * j]);
                ekT[cg + 2 * j][tl]     = __expf(kf.x - smM[cg + 2 * j]);
                ekT[cg + 2 * j + 1][tl] = __expf(kf.y - smM[cg + 2 * j + 1]);
                vT[cg + 2 * j][tl]      = vf.x;
                vT[cg + 2 * j + 1][tl]  = vf.y;
            }
        } else {
            #pragma unroll
            for (int j = 0; j < 12; ++j) {
                ekT[cg + j][tl] = 0.f;
                vT[cg + j][tl]  = 0.f;
            }
        }
        __syncthreads();
        s16x8 af[3], bfr[3];
        #pragma unroll
        for (int i = 0; i < 3; ++i)
            af[i] = cvt8(&ekT[wd * 48 + i * 16 + l15][q4 * 8]);
        #pragma unroll
        for (int i = 0; i < 3; ++i)
            bfr[i] = cvt8(&vT[we * 48 + i * 16 + l15][q4 * 8]);
        #pragma unroll
        for (int i = 0; i < 3; ++i)
            #pragma unroll
            for (int j = 0; j < 3; ++j)
                acc[i][j] = __builtin_amdgcn_mfma_f32_16x16x32_bf16(
                    af[i], bfr[j], acc[i][j], 0, 0, 0);
        __syncthreads();
    }
    float* abase = attn_part + (size_t)ns * BN * NH * HD * HD
                 + (size_t)(b * NH + h) * HD * HD;
    #pragma unroll
    for (int i = 0; i < 3; ++i)
        #pragma unroll
        for (int j = 0; j < 3; ++j)
            #pragma unroll
            for (int r = 0; r < 4; ++r)
                abase[(size_t)(wd * 48 + i * 16 + q4 * 4 + r) * HD
                      + we * 48 + j * 16 + l15] = acc[i][j][r];
}

// ---------------------------------------------------------------------------
// K3b: attn[b,h,d,e] = stat_is[b,h*96+d] * sum_s attn_part[s][b,h,d,e]
// ---------------------------------------------------------------------------
__global__ __launch_bounds__(256)
void attn_reduce_kernel(const float* __restrict__ part,
                        const float* __restrict__ stat_is,
                        float* __restrict__ attn) {
    const int TOT4 = BN * NH * HD * HD / 4;   // 589824
    int i = blockIdx.x * 256 + threadIdx.x;
    if (i >= TOT4) return;
    size_t base = (size_t)i * 4;
    int bh = (int)(base / (HD * HD));
    int d  = (int)((base / HD) % HD);
    float is = stat_is[(bh >> 3) * DIM + (bh & 7) * HD + d];
    const size_t PSZ = (size_t)BN * NH * HD * HD;
    float4 s = *(const float4*)&part[base];
    float4 p1 = *(const float4*)&part[PSZ + base];
    float4 p2 = *(const float4*)&part[2 * PSZ + base];
    float4 p3 = *(const float4*)&part[3 * PSZ + base];
    s.x = (s.x + p1.x + p2.x + p3.x) * is;
    s.y = (s.y + p1.y + p2.y + p3.y) * is;
    s.z = (s.z + p1.z + p2.z + p3.z) * is;
    s.w = (s.w + p1.w + p2.w + p3.w) * is;
    *(float4*)&attn[base] = s;
}

// ---------------------------------------------------------------------------
// K4: CRPE depthwise conv (r2 structure, verified).
// ---------------------------------------------------------------------------
#define CRS 1104   // conv tile row stride in bf16 elems (34*32 + 16 pad)

template<int KS>
__device__ __forceinline__ void crpe_conv32(const ushort_t* __restrict__ vimg,
                                            const float* __restrict__ wsm,
                                            float b0, float b1,
                                            ushort_t* __restrict__ ob,
                                            int p, int yl, int y) {
    constexpr int R = KS / 2;
    const float* wA = wsm + (2 * p) * KS * KS;
    const float* wB = wA + KS * KS;
    #pragma unroll
    for (int xo = 0; xo < 28; xo += 7) {
        float a0[7], a1[7];
        #pragma unroll
        for (int u = 0; u < 7; ++u) { a0[u] = b0; a1[u] = b1; }
        #pragma unroll
        for (int ky = 0; ky < KS; ++ky) {
            const ushort_t* rp = vimg + (yl + ky - R + 3) * CRS
                                      + (xo - R + 3) * 32 + 2 * p;
            float2 seg[6 + KS];
            #pragma unroll
            for (int i = 0; i < 6 + KS; ++i)
                seg[i] = __bfloat1622float2(*(const __hip_bfloat162*)(rp + i * 32));
            #pragma unroll
            for (int kx = 0; kx < KS; ++kx) {
                float wa = wA[ky * KS + kx];
                float wb = wB[ky * KS + kx];
                #pragma unroll
                for (int u = 0; u < 7; ++u) {
                    a0[u] = fmaf(wa, seg[u + kx].x, a0[u]);
                    a1[u] = fmaf(wb, seg[u + kx].y, a1[u]);
                }
            }
        }
        #pragma unroll
        for (int u = 0; u < 7; ++u)
            *(__hip_bfloat162*)&ob[(size_t)(1 + y * GW + xo + u) * DIM + 2 * p] =
                __float22bfloat162_rn(make_float2(a0[u], a1[u]));
    }
}

__global__ __launch_bounds__(256)
void crpe_lds_kernel(const ushort_t* __restrict__ v,
                     const float* __restrict__ w3, const float* __restrict__ b3,
                     const float* __restrict__ w5, const float* __restrict__ b5,
                     const float* __restrict__ w7, const float* __restrict__ b7,
                     ushort_t* __restrict__ o) {
    __shared__ ushort_t vimg[20 * CRS];   // 44,160 B
    __shared__ float    wsm[32 * 49];     //  6,272 B
    const int cg  = blockIdx.x;    // 0..23, 32-channel group
    const int hf  = blockIdx.y;    // 0..1 image half (rows 0..13 / 14..27)
    const int b   = blockIdx.z;
    const int tid = threadIdx.x;
    const int c0  = cg * 32;

    const float* wsrc; const float* bsrc; int ks;
    if (c0 < 192)      { wsrc = w3 + c0 * 9;          bsrc = b3 + c0;         ks = 3; }
    else if (c0 < 480) { wsrc = w5 + (c0 - 192) * 25; bsrc = b5 + (c0 - 192); ks = 5; }
    else               { wsrc = w7 + (c0 - 480) * 49; bsrc = b7 + (c0 - 480); ks = 7; }
    const int ksq = ks * ks;

    const int zr0 = hf ? 17 : 0;
    for (int idx = tid; idx < 3 * 138; idx += 256) {
        int rr = idx / 138, cc = idx - rr * 138;
        *(s16x8*)&vimg[(zr0 + rr) * CRS + cc * 8] = (s16x8){0,0,0,0,0,0,0,0};
    }
    for (int idx = tid; idx < 17 * 24; idx += 256) {
        int vr = idx / 24, cc = idx - vr * 24;
        int ly = hf ? vr : vr + 3;
        int ch = (cc < 12) ? cc : (112 + cc);
        *(s16x8*)&vimg[ly * CRS + ch * 8] = (s16x8){0,0,0,0,0,0,0,0};
    }
    for (int idx = tid; idx < 32 * ksq; idx += 256)
        wsm[idx] = wsrc[idx];
    const ushort_t* vb = v + (size_t)b * NTOK * DIM + c0;
    const int gy0 = hf ? 11 : 0;
    for (int idx = tid; idx < 17 * 28 * 4; idx += 256) {
        int vr = idx / 112, rem = idx - vr * 112;
        int px = rem >> 2, c8 = rem & 3;
        int gy = gy0 + vr;
        int ly = hf ? vr : vr + 3;
        *(s16x8*)&vimg[ly * CRS + (px + 3) * 32 + c8 * 8] =
            *(const s16x8*)(vb + (size_t)(1 + gy * GW + px) * DIM + c8 * 8);
    }
    ushort_t* ob = o + (size_t)b * NTOK * DIM + c0;
    if (hf == 0 && tid < 32) ob[tid] = 0;   // CLS row: rp = 0
    __syncthreads();

    const int p  = tid & 15;       // channel pair 0..15
    const int yl = tid >> 4;       // row within half 0..15
    if (yl >= 14) return;
    const int y = hf * 14 + yl;    // global row
    float bb0 = bsrc[2 * p], bb1 = bsrc[2 * p + 1];
    if (ks == 3)      crpe_conv32<3>(vimg, wsm, bb0, bb1, ob, p, yl, y);
    else if (ks == 5) crpe_conv32<5>(vimg, wsm, bb0, bb1, ob, p, yl, y);
    else              crpe_conv32<7>(vimg, wsm, bb0, bb1, ob, p, yl, y);
}

// ---------------------------------------------------------------------------
// K5: o[b,n,h*96+e] = scale * sum_d q[n,d] attn[d,e] + q[n,e] * rp (in-place)
// MFMA version (r6, verified).
// ---------------------------------------------------------------------------
__global__ __launch_bounds__(256)
void combine_kernel(const ushort_t* __restrict__ q, const float* __restrict__ attn,
                    ushort_t* __restrict__ o) {
    const int h = blockIdx.x, b = blockIdx.z;
    const int n0 = blockIdx.y * 64;
    const int t = threadIdx.x;
    const int wave = t >> 6, lane = t & 63;
    const int q4 = lane >> 4, l15 = lane & 15;
    __shared__ ushort_t qs[64][104];
    __shared__ ushort_t atT[96][104];

    const ushort_t* qbase = q + (size_t)b * NTOK * DIM + h * HD;
    #pragma unroll
    for (int i = 0; i < 3; ++i) {
        int idx = t + i * 256;          // 0..767 = 64 rows x 12 chunks
        int rr = idx / 12, c8 = idx % 12;
        int n = n0 + rr;
        s16x8 val = (s16x8){0,0,0,0,0,0,0,0};
        if (n < NTOK) val = *(const s16x8*)(qbase + (size_t)n * DIM + c8 * 8);
        *(s16x8*)&qs[rr][c8 * 8] = val;
    }
    const float* abase = attn + (size_t)(b * NH + h) * HD * HD;
    #pragma unroll
    for (int i = 0; i < 36; ++i) {
        int idx = t + i * 256;          // 0..9215; read coalesced [d][e]
        int d = idx / 96, e = idx % 96;
        atT[e][d] = f2bf(abase[idx]);
    }
    __syncthreads();

    f32x4 acc[6];
    #pragma unroll
    for (int i = 0; i < 6; ++i) acc[i] = (f32x4){0.f, 0.f, 0.f, 0.f};
    #pragma unroll
    for (int ks = 0; ks < 3; ++ks) {
        s16x8 aq = *(const s16x8*)&qs[wave * 16 + l15][ks * 32 + q4 * 8];
        #pragma unroll
        for (int et = 0; et < 6; ++et) {
            s16x8 bfrg = *(const s16x8*)&atT[et * 16 + l15][ks * 32 + q4 * 8];
            acc[et] = __builtin_amdgcn_mfma_f32_16x16x32_bf16(
                aq, bfrg, acc[et], 0, 0, 0);
        }
    }

    const float scale = 0.10206207261596575f;  // 96^-0.5
    ushort_t* obase = o + (size_t)b * NTOK * DIM + h * HD;
    #pragma unroll
    for (int et = 0; et < 6; ++et) {
        int e = et * 16 + l15;
        #pragma unroll
        for (int r = 0; r < 4; ++r) {
            int rr = wave * 16 + q4 * 4 + r;
            int n = n0 + rr;
            if (n >= NTOK) continue;
            size_t oa = (size_t)n * DIM + e;
            float rp = __bfloat162float(*(const bf16*)&obase[oa]);
            float qv = __bfloat162float(*(const bf16*)&qs[rr][e]);
            obase[oa] = f2bf(scale * acc[et][r] + qv * rp);
        }
    }
}

// ---------------------------------------------------------------------------
extern "C" void kernel_launch(void* const* d_in, const int* in_sizes, int n_in,
                              void* d_out, int out_size, void* d_ws, size_t ws_size,
                              hipStream_t stream) {
    const float* x     = (const float*)d_in[0];
    const float* W_qkv = (const float*)d_in[1];
    const float* b_qkv = (const float*)d_in[2];
    const float* W_out = (const float*)d_in[3];
    const float* b_out = (const float*)d_in[4];
    const float* w3    = (const float*)d_in[5];
    const float* cb3   = (const float*)d_in[6];
    const float* w5    = (const float*)d_in[7];
    const float* cb5   = (const float*)d_in[8];
    const float* w7    = (const float*)d_in[9];
    const float* cb7   = (const float*)d_in[10];
    float* out = (float*)d_out;

    ushort_t* q = (ushort_t*)d_ws;
    ushort_t* k = q + (size_t)MROWS * DIM;
    ushort_t* v = k + (size_t)MROWS * DIM;
    float* attn    = (float*)(v + (size_t)MROWS * DIM);
    float* stat_m  = attn + (size_t)BN * NH * HD * HD;
    float* stat_is = stat_m + (size_t)BN * DIM;
    ushort_t* Wqkvt = (ushort_t*)(stat_is + (size_t)BN * DIM);
    ushort_t* Wot   = Wqkvt + (size_t)QKVD * DIM;
    ushort_t* o = k;   // alias: k dead after attn_kernel

    // d_out scratch layout: xb (bf16 x, 38.58 MB) then attn_part (37.75 MB).
    // Both dead before gemm_out_mfma writes d_out (77.17 MB total).
    ushort_t* xb = (ushort_t*)d_out;
    float* attn_part = (float*)d_out + (size_t)MROWS * DIM / 2;

    prep_kernel<<<dim3(TQKV + TOUT + NCONV), 256, 0, stream>>>(
        W_qkv, Wqkvt, W_out, Wot, x, xb);
    gemm_qkv_mfma<<<dim3(QKVD / 128, (MROWS + 127) / 128), 256, 0, stream>>>(
        xb, Wqkvt, b_qkv, q, k, v);
    softmax_stats_kernel<<<dim3(24, BN), 256, 0, stream>>>(
        k, stat_m, stat_is);
    attn_kernel<<<dim3(NH, BN, NS), 256, 0, stream>>>(
        (const bf16*)k, (const bf16*)v, stat_m, attn_part);
    {
        int tot4 = BN * NH * HD * HD / 4;
        attn_reduce_kernel<<<dim3((tot4 + 255) / 256), 256, 0, stream>>>(
            attn_part, stat_is, attn);
    }
    crpe_lds_kernel<<<dim3(24, 2, BN), 256, 0, stream>>>(
        v, w3, cb3, w5, cb5, w7, cb7, o);
    combine_kernel<<<dim3(NH, 13, BN), 256, 0, stream>>>(
        q, attn, o);
    gemm_out_mfma<<<dim3(DIM / 128, (MROWS + 127) / 128), 256, 0, stream>>>(
        o, Wot, b_out, out);
}